// Round 2
// baseline (2262.912 us; speedup 1.0000x reference)
//
#include <hip/hip_runtime.h>

// Centroids: for each latent row (131072 x 128 f32), argmin over 2048 coords
// of squared euclidean distance. Output int32 indices.
//
// Two-phase exact-argmin:
//   Phase 1 (fp32): score(c) = c2[c] - 2*dot(x,coord[c]) (x^2 dropped, argmin-
//     invariant). Tracks best + second-best; rows with gap < MARGIN go to a
//     worklist (near-tie: fp32 rounding ~2.5e-3 can flip vs the fp64 ref).
//   Phase 2 (fp64): flagged rows recompute all 2048 true d2 in double and
//     overwrite out[row]. ~1% of rows expected -> negligible cost.
//
// d_ws layout (floats/ints, 4B units):
//   [0, 2048)      c2 (f32)
//   [2048]         worklist counter (int, zeroed by c2_kernel each call)
//   [2052, ...)    worklist (int row ids), capacity from ws_size

constexpr int D   = 128;
constexpr int C   = 2048;
constexpr int BLK = 256;
constexpr int TC  = 64;      // coords per LDS tile
constexpr float MARGIN = 0.05f;  // ~20x fp32 score error bound

__global__ void c2_kernel(const float* __restrict__ coords, float* __restrict__ c2,
                          int* __restrict__ counter) {
    int c = blockIdx.x * blockDim.x + threadIdx.x;
    if (c == 0) *counter = 0;          // d_ws is re-poisoned before every call
    if (c >= C) return;
    const float* p = coords + (size_t)c * D;
    float s = 0.f;
#pragma unroll
    for (int k = 0; k < D; k += 4) {
        float4 v = *(const float4*)(p + k);
        s = fmaf(v.x, v.x, s);
        s = fmaf(v.y, v.y, s);
        s = fmaf(v.z, v.z, s);
        s = fmaf(v.w, v.w, s);
    }
    c2[c] = s;
}

__global__ __launch_bounds__(BLK) void centroid_argmin(
        const float* __restrict__ latent,
        const float* __restrict__ coords,
        const float* __restrict__ c2,
        int* __restrict__ out,
        int* __restrict__ counter,
        int* __restrict__ worklist,
        int wl_cap) {
    __shared__ float sc[TC * D];   // 32 KB coord tile
    __shared__ float sc2[TC];

    const int row = blockIdx.x * BLK + threadIdx.x;

    float x[D];
    {
        const float* lp = latent + (size_t)row * D;
#pragma unroll
        for (int k = 0; k < D; k += 4) {
            float4 v = *(const float4*)(lp + k);
            x[k]     = v.x;
            x[k + 1] = v.y;
            x[k + 2] = v.z;
            x[k + 3] = v.w;
        }
    }

    float best  = 3.4e38f;
    float best2 = 3.4e38f;
    int   bidx  = 0;

    for (int t0 = 0; t0 < C; t0 += TC) {
        __syncthreads();
#pragma unroll
        for (int i = 0; i < (TC * D) / (BLK * 4); ++i) {
            int idx4 = i * BLK + threadIdx.x;
            float4 v = *(const float4*)(coords + (size_t)t0 * D + idx4 * 4);
            *(float4*)(sc + idx4 * 4) = v;
        }
        if (threadIdx.x < TC) sc2[threadIdx.x] = c2[t0 + threadIdx.x];
        __syncthreads();

#pragma unroll 1
        for (int c = 0; c < TC; c += 2) {
            const float* p0 = sc + c * D;
            const float* p1 = sc + (c + 1) * D;
            float a0 = 0.f, a1 = 0.f, b0 = 0.f, b1 = 0.f;
#pragma unroll
            for (int k = 0; k < D; k += 4) {
                float4 c0 = *(const float4*)(p0 + k);  // wave-uniform broadcast
                float4 c1 = *(const float4*)(p1 + k);
                a0 = fmaf(x[k],     c0.x, a0);
                a1 = fmaf(x[k + 1], c0.y, a1);
                a0 = fmaf(x[k + 2], c0.z, a0);
                a1 = fmaf(x[k + 3], c0.w, a1);
                b0 = fmaf(x[k],     c1.x, b0);
                b1 = fmaf(x[k + 1], c1.y, b1);
                b0 = fmaf(x[k + 2], c1.z, b0);
                b1 = fmaf(x[k + 3], c1.w, b1);
            }
            float s0 = sc2[c]     - 2.f * (a0 + a1);
            float s1 = sc2[c + 1] - 2.f * (b0 + b1);
            // ascending scan + strict < => first-occurrence, matches argmin
            if (s0 < best) { best2 = best; best = s0; bidx = t0 + c; }
            else if (s0 < best2) { best2 = s0; }
            if (s1 < best) { best2 = best; best = s1; bidx = t0 + c + 1; }
            else if (s1 < best2) { best2 = s1; }
        }
    }
    out[row] = bidx;
    if (best2 - best < MARGIN) {           // near-tie: needs fp64 arbitration
        int w = atomicAdd(counter, 1);
        if (w < wl_cap) worklist[w] = row;
    }
}

__global__ __launch_bounds__(256) void refine_fp64(
        const float* __restrict__ latent,
        const float* __restrict__ coords,
        const int* __restrict__ worklist,
        const int* __restrict__ counter,
        int wl_cap,
        int* __restrict__ out) {
    __shared__ float  xs[D];
    __shared__ double rv[256];
    __shared__ int    ri[256];

    int n = *counter;
    if (n > wl_cap) n = wl_cap;

    for (int wi = blockIdx.x; wi < n; wi += gridDim.x) {
        int row = worklist[wi];
        if (threadIdx.x < D)
            xs[threadIdx.x] = latent[(size_t)row * D + threadIdx.x];
        __syncthreads();

        double best = 1.0e300;
        int    bidx = 0;
        for (int c = threadIdx.x; c < C; c += 256) {
            const float* cp = coords + (size_t)c * D;
            double s = 0.0;
#pragma unroll 16
            for (int k = 0; k < D; ++k) {
                double d = (double)xs[k] - (double)cp[k];
                s = fma(d, d, s);
            }
            if (s < best) { best = s; bidx = c; }  // ascending per-thread scan
        }
        rv[threadIdx.x] = best;
        ri[threadIdx.x] = bidx;
        __syncthreads();
        for (int off = 128; off > 0; off >>= 1) {
            if (threadIdx.x < off) {
                double ov = rv[threadIdx.x + off];
                int    oi = ri[threadIdx.x + off];
                if (ov < rv[threadIdx.x] ||
                    (ov == rv[threadIdx.x] && oi < ri[threadIdx.x])) {
                    rv[threadIdx.x] = ov;
                    ri[threadIdx.x] = oi;
                }
            }
            __syncthreads();
        }
        if (threadIdx.x == 0) out[row] = ri[0];
        __syncthreads();   // protect xs before next worklist row
    }
}

extern "C" void kernel_launch(void* const* d_in, const int* in_sizes, int n_in,
                              void* d_out, int out_size, void* d_ws, size_t ws_size,
                              hipStream_t stream) {
    const float* latent = (const float*)d_in[0];   // 131072 x 128 f32
    const float* coords = (const float*)d_in[1];   // 2048 x 128 f32
    int*         out    = (int*)d_out;             // 131072 int32

    float* c2       = (float*)d_ws;
    int*   counter  = (int*)d_ws + 2048;
    int*   worklist = (int*)d_ws + 2052;
    long long cap_ll = (long long)(ws_size / 4) - 2052;
    int wl_cap = cap_ll < 0 ? 0 : (cap_ll > (1 << 20) ? (1 << 20) : (int)cap_ll);

    const int n_rows = in_sizes[0] / D;            // 131072

    c2_kernel<<<(C + BLK - 1) / BLK, BLK, 0, stream>>>(coords, c2, counter);
    centroid_argmin<<<n_rows / BLK, BLK, 0, stream>>>(latent, coords, c2, out,
                                                      counter, worklist, wl_cap);
    refine_fp64<<<608, 256, 0, stream>>>(latent, coords, worklist, counter,
                                         wl_cap, out);
}

// Round 4
// 574.951 us; speedup vs baseline: 3.9358x; 3.9358x over previous
//
#include <hip/hip_runtime.h>

// Centroids: argmin_c ||latent[r] - coords[c]||^2 for 131072 rows, 2048 coords, D=128.
//
// Phase 0: c2[c] = ||coords[c]||^2 (fp32), zero worklist counter.
// Phase 1: MFMA bf16x2. cross = latent @ coords^T via 3 passes
//          (Ahi*Bhi + Ahi*Blo + Alo*Bhi); score = c2 - 2*cross.
//          Per-slot running (best, best2, idx); butterfly merge across the 16
//          col-residue lanes; LDS exchange merges the two wn wave-halves
//          (R3 bug: both halves raced on out[row] without merging).
//          Rows with gap < MARGIN flagged.
// Phase 2: fp64 exact recompute for flagged rows (~1%), overwrites out[row].
//
// ws layout (4B units): [0,2048) c2 | [2048] counter | [2052..) worklist

constexpr int D       = 128;
constexpr int C       = 2048;
constexpr int M_TILE  = 128;   // rows per block
constexpr int N_CHUNK = 128;   // coords per chunk
constexpr int LDK     = 136;   // padded k-stride (bf16 elems)
constexpr float MARGIN = 0.05f;

typedef __attribute__((ext_vector_type(8))) short short8;
typedef __attribute__((ext_vector_type(4))) float f32x4;

__global__ void c2_kernel(const float* __restrict__ coords, float* __restrict__ c2,
                          int* __restrict__ counter) {
    int c = blockIdx.x * blockDim.x + threadIdx.x;
    if (c == 0) *counter = 0;
    if (c >= C) return;
    const float* p = coords + (size_t)c * D;
    float s = 0.f;
#pragma unroll
    for (int k = 0; k < D; k += 4) {
        float4 v = *(const float4*)(p + k);
        s = fmaf(v.x, v.x, s); s = fmaf(v.y, v.y, s);
        s = fmaf(v.z, v.z, s); s = fmaf(v.w, v.w, s);
    }
    c2[c] = s;
}

__device__ inline unsigned short bf16_rne(float x) {
    unsigned u = __float_as_uint(x);
    u += 0x7FFFu + ((u >> 16) & 1u);
    return (unsigned short)(u >> 16);
}
__device__ inline float bf16_to_f(unsigned short h) {
    return __uint_as_float(((unsigned)h) << 16);
}

// Convert a 128x128 f32 tile (contiguous rows, stride D) into hi/lo bf16 LDS
// arrays with padded stride LDK. 256 threads, 16 float4 each, coalesced.
__device__ inline void stage_tile(const float* __restrict__ src,
                                  unsigned short* __restrict__ hi,
                                  unsigned short* __restrict__ lo, int tid) {
#pragma unroll
    for (int i = 0; i < 16; ++i) {
        int f   = i * 256 + tid;      // float4 index in 128x128 tile
        int row = f >> 5;             // 32 float4 per row
        int c4  = f & 31;
        float4 v = *(const float4*)(src + (size_t)row * D + c4 * 4);
        unsigned short h0 = bf16_rne(v.x), h1 = bf16_rne(v.y),
                       h2 = bf16_rne(v.z), h3 = bf16_rne(v.w);
        unsigned short l0 = bf16_rne(v.x - bf16_to_f(h0)),
                       l1 = bf16_rne(v.y - bf16_to_f(h1)),
                       l2 = bf16_rne(v.z - bf16_to_f(h2)),
                       l3 = bf16_rne(v.w - bf16_to_f(h3));
        uint2 hp, lp;
        hp.x = (unsigned)h0 | ((unsigned)h1 << 16);
        hp.y = (unsigned)h2 | ((unsigned)h3 << 16);
        lp.x = (unsigned)l0 | ((unsigned)l1 << 16);
        lp.y = (unsigned)l2 | ((unsigned)l3 << 16);
        *(uint2*)(hi + row * LDK + c4 * 4) = hp;
        *(uint2*)(lo + row * LDK + c4 * 4) = lp;
    }
}

__global__ __launch_bounds__(256, 1) void centroid_mfma(
        const float* __restrict__ latent,
        const float* __restrict__ coords,
        const float* __restrict__ c2g,
        int* __restrict__ out,
        int* __restrict__ counter,
        int* __restrict__ worklist,
        int wl_cap) {
    __shared__ unsigned short A_hi[M_TILE * LDK], A_lo[M_TILE * LDK];
    __shared__ unsigned short B_hi[N_CHUNK * LDK], B_lo[N_CHUNK * LDK];
    __shared__ float sc2[N_CHUNK];
    __shared__ float xb1[M_TILE], xb2[M_TILE];   // wn=1 -> wn=0 exchange
    __shared__ int   xix[M_TILE];

    const int tid  = threadIdx.x;
    const int wid  = tid >> 6;
    const int lane = tid & 63;
    const int wm   = wid >> 1;           // wave row 0..1   (64-row slice)
    const int wn   = wid & 1;            // wave col 0..1   (64-col slice)
    const int q    = lane >> 4;          // quad 0..3
    const int lr   = lane & 15;
    const int row_block = blockIdx.x * M_TILE;

    stage_tile(latent + (size_t)row_block * D, A_hi, A_lo, tid);

    float b1[16], b2[16];
    int   bidx[16];
#pragma unroll
    for (int s = 0; s < 16; ++s) { b1[s] = 3.4e38f; b2[s] = 3.4e38f; bidx[s] = 0; }

    for (int ch = 0; ch < C / N_CHUNK; ++ch) {
        __syncthreads();   // prior chunk's frag reads done (and A staging on ch=0)
        stage_tile(coords + (size_t)ch * N_CHUNK * D, B_hi, B_lo, tid);
        if (tid < N_CHUNK) sc2[tid] = c2g[ch * N_CHUNK + tid];
        __syncthreads();

        f32x4 acc[4][4];
#pragma unroll
        for (int mt = 0; mt < 4; ++mt)
#pragma unroll
            for (int nt = 0; nt < 4; ++nt)
                acc[mt][nt] = (f32x4){0.f, 0.f, 0.f, 0.f};

#pragma unroll
        for (int ks = 0; ks < 4; ++ks) {
            short8 ah[4], al[4], bh[4], bl[4];
#pragma unroll
            for (int mt = 0; mt < 4; ++mt) {
                int off = (wm * 64 + mt * 16 + lr) * LDK + ks * 32 + q * 8;
                ah[mt] = *(const short8*)(A_hi + off);
                al[mt] = *(const short8*)(A_lo + off);
            }
#pragma unroll
            for (int nt = 0; nt < 4; ++nt) {
                int off = (wn * 64 + nt * 16 + lr) * LDK + ks * 32 + q * 8;
                bh[nt] = *(const short8*)(B_hi + off);
                bl[nt] = *(const short8*)(B_lo + off);
            }
#pragma unroll
            for (int mt = 0; mt < 4; ++mt)
#pragma unroll
                for (int nt = 0; nt < 4; ++nt) {
                    acc[mt][nt] = __builtin_amdgcn_mfma_f32_16x16x32_bf16(
                        ah[mt], bh[nt], acc[mt][nt], 0, 0, 0);
                    acc[mt][nt] = __builtin_amdgcn_mfma_f32_16x16x32_bf16(
                        ah[mt], bl[nt], acc[mt][nt], 0, 0, 0);
                    acc[mt][nt] = __builtin_amdgcn_mfma_f32_16x16x32_bf16(
                        al[mt], bh[nt], acc[mt][nt], 0, 0, 0);
                }
        }

        // Epilogue: score = c2 - 2*cross; per-slot running (b1,b2,idx).
        // C/D layout: col = lane&15, row = (lane>>4)*4 + reg  [m89/m91 verified]
#pragma unroll
        for (int nt = 0; nt < 4; ++nt) {
            int cix = wn * 64 + nt * 16 + lr;       // col within chunk
            float c2v = sc2[cix];
            int n_global = ch * N_CHUNK + cix;
#pragma unroll
            for (int mt = 0; mt < 4; ++mt)
#pragma unroll
                for (int r = 0; r < 4; ++r) {
                    int slot = mt * 4 + r;
                    float s = fmaf(-2.f, acc[mt][nt][r], c2v);
                    bool lt = s < b1[slot];
                    float t = fmaxf(s, b1[slot]);
                    b2[slot]   = fminf(b2[slot], t);
                    b1[slot]   = fminf(s, b1[slot]);
                    bidx[slot] = lt ? n_global : bidx[slot];
                }
        }
    }

    // Cross-lane merge over col-residues (lanes lr = 0..15 within each quad).
#pragma unroll
    for (int m = 1; m <= 8; m <<= 1) {
#pragma unroll
        for (int s = 0; s < 16; ++s) {
            float ob1 = __shfl_xor(b1[s], m, 64);
            float ob2 = __shfl_xor(b2[s], m, 64);
            int   oix = __shfl_xor(bidx[s], m, 64);
            float mx  = fmaxf(b1[s], ob1);
            b2[s] = fminf(fminf(b2[s], ob2), mx);
            bool take = (ob1 < b1[s]) || (ob1 == b1[s] && oix < bidx[s]);
            b1[s]   = take ? ob1 : b1[s];
            bidx[s] = take ? oix : bidx[s];
        }
    }

    // Merge the two column-halves (wn=1 publishes, wn=0 combines + writes).
    // After the butterfly, lane with lr==s holds canonical slot s for row
    // wm*64 + (s>>2)*16 + q*4 + (s&3).
    if (wn == 1) {
#pragma unroll
        for (int s = 0; s < 16; ++s)
            if (lr == s) {
                int rw = wm * 64 + (s >> 2) * 16 + q * 4 + (s & 3);
                xb1[rw] = b1[s]; xb2[rw] = b2[s]; xix[rw] = bidx[s];
            }
    }
    __syncthreads();
    if (wn == 0) {
#pragma unroll
        for (int s = 0; s < 16; ++s)
            if (lr == s) {
                int rw = wm * 64 + (s >> 2) * 16 + q * 4 + (s & 3);
                float ob1 = xb1[rw], ob2 = xb2[rw];
                int   oix = xix[rw];
                float mx  = fmaxf(b1[s], ob1);
                float nb2 = fminf(fminf(b2[s], ob2), mx);
                bool take = (ob1 < b1[s]) || (ob1 == b1[s] && oix < bidx[s]);
                float nb1 = take ? ob1 : b1[s];
                int   nix = take ? oix : bidx[s];
                out[row_block + rw] = nix;
                if (nb2 - nb1 < MARGIN) {      // near-tie: fp64 arbitration
                    int w = atomicAdd(counter, 1);
                    if (w < wl_cap) worklist[w] = row_block + rw;
                }
            }
    }
}

__global__ __launch_bounds__(256) void refine_fp64(
        const float* __restrict__ latent,
        const float* __restrict__ coords,
        const int* __restrict__ worklist,
        const int* __restrict__ counter,
        int wl_cap,
        int* __restrict__ out) {
    __shared__ float  xs[D];
    __shared__ double rv[256];
    __shared__ int    ri[256];

    int n = *counter;
    if (n > wl_cap) n = wl_cap;

    for (int wi = blockIdx.x; wi < n; wi += gridDim.x) {
        int row = worklist[wi];
        if (threadIdx.x < D)
            xs[threadIdx.x] = latent[(size_t)row * D + threadIdx.x];
        __syncthreads();

        double best = 1.0e300;
        int    bidx = 0;
        for (int c = threadIdx.x; c < C; c += 256) {
            const float* cp = coords + (size_t)c * D;
            double s = 0.0;
#pragma unroll 16
            for (int k = 0; k < D; ++k) {
                double d = (double)xs[k] - (double)cp[k];
                s = fma(d, d, s);
            }
            if (s < best) { best = s; bidx = c; }
        }
        rv[threadIdx.x] = best;
        ri[threadIdx.x] = bidx;
        __syncthreads();
        for (int off = 128; off > 0; off >>= 1) {
            if (threadIdx.x < off) {
                double ov = rv[threadIdx.x + off];
                int    oi = ri[threadIdx.x + off];
                if (ov < rv[threadIdx.x] ||
                    (ov == rv[threadIdx.x] && oi < ri[threadIdx.x])) {
                    rv[threadIdx.x] = ov;
                    ri[threadIdx.x] = oi;
                }
            }
            __syncthreads();
        }
        if (threadIdx.x == 0) out[row] = ri[0];
        __syncthreads();
    }
}

extern "C" void kernel_launch(void* const* d_in, const int* in_sizes, int n_in,
                              void* d_out, int out_size, void* d_ws, size_t ws_size,
                              hipStream_t stream) {
    const float* latent = (const float*)d_in[0];   // 131072 x 128 f32
    const float* coords = (const float*)d_in[1];   // 2048 x 128 f32
    int*         out    = (int*)d_out;             // 131072 int32

    float* c2       = (float*)d_ws;
    int*   counter  = (int*)d_ws + 2048;
    int*   worklist = (int*)d_ws + 2052;
    long long cap_ll = (long long)(ws_size / 4) - 2052;
    int wl_cap = cap_ll < 0 ? 0 : (cap_ll > (1 << 20) ? (1 << 20) : (int)cap_ll);

    const int n_rows = in_sizes[0] / D;            // 131072

    c2_kernel<<<(C + 255) / 256, 256, 0, stream>>>(coords, c2, counter);
    centroid_mfma<<<n_rows / M_TILE, 256, 0, stream>>>(latent, coords, c2, out,
                                                       counter, worklist, wl_cap);
    refine_fp64<<<608, 256, 0, stream>>>(latent, coords, worklist, counter,
                                         wl_cap, out);
}

// Round 5
// 538.578 us; speedup vs baseline: 4.2016x; 1.0675x over previous
//
#include <hip/hip_runtime.h>

// Centroids: argmin_c ||latent[r] - coords[c]||^2, 131072 rows x 2048 coords, D=128.
//
// Fast path (ws >= 66 MB):
//   prep_coords: coords -> bf16 hi/lo "B images" (XOR-swizzled granules so the
//     LDS copy is contiguous AND frag ds_read_b128 is bank-conflict-free),
//     plus c2 and counter=0.
//   prep_latent: latent -> bf16 hi/lo "A images" in fragment-major order so
//     each wave's A fragment is one contiguous 1 KB global dwordx4 load.
//     A frags live in VGPRs across all 16 chunks (no LDS for A).
//   centroid_fast: per chunk: stage 64 KB B (contiguous), 32 ds_read_b128,
//     192 MFMA (bf16x2 3-pass), fused argmin epilogue w/ best/best2 tracking.
//   refine_fp64: rows with gap < MARGIN recomputed exactly in fp64.
// Fallback path (small ws): R3 kernel set (in-kernel conversion), verified.
//
// ws layout (bytes):
//   0        c2 (2048 f32)
//   8192     counter (int)
//   16384    worklist (32768 int)
//   262144   B_hi image (512 KB)   786432   B_lo image (512 KB)
//   2097152  A_hi image (32 MB)    35651584 A_lo image (32 MB)   end 69206016

constexpr int D = 128;
constexpr int C = 2048;
constexpr float MARGIN = 0.02f;   // bf16x2 worst-case score err ~5e-3 -> 4x headroom
constexpr int WL_CAP = 32768;

constexpr size_t WS_CNT = 8192;
constexpr size_t WS_WL  = 16384;
constexpr size_t WS_BH  = 262144;
constexpr size_t WS_BL  = 786432;
constexpr size_t WS_AH  = 2097152;
constexpr size_t WS_AL  = 35651584;
constexpr size_t WS_END = 69206016;

typedef __attribute__((ext_vector_type(8))) short short8;
typedef __attribute__((ext_vector_type(4))) float f32x4;

__device__ inline unsigned short bf16_rne(float x) {
    unsigned u = __float_as_uint(x);
    u += 0x7FFFu + ((u >> 16) & 1u);
    return (unsigned short)(u >> 16);
}
__device__ inline float bf16_to_f(unsigned short h) {
    return __uint_as_float(((unsigned)h) << 16);
}

// Pack 8 floats' hi/lo bf16 into two short8s.
__device__ inline void split8(const float* v, short8* hi, short8* lo) {
#pragma unroll
    for (int j = 0; j < 8; ++j) {
        unsigned short h = bf16_rne(v[j]);
        (*hi)[j] = (short)h;
        (*lo)[j] = (short)bf16_rne(v[j] - bf16_to_f(h));
    }
}

// ---------------- fast-path prep kernels ----------------

// 32768 threads: thread t handles coord c = t>>4, k-granule k8 = t&15.
__global__ void prep_coords(const float* __restrict__ coords,
                            unsigned short* __restrict__ Bh,
                            unsigned short* __restrict__ Bl,
                            float* __restrict__ c2, int* __restrict__ counter) {
    int t = blockIdx.x * blockDim.x + threadIdx.x;
    if (t == 0) *counter = 0;
    if (t >= C * 16) return;
    int c  = t >> 4;
    int k8 = t & 15;
    float v[8];
    *(float4*)(v)     = *(const float4*)(coords + (size_t)c * D + k8 * 8);
    *(float4*)(v + 4) = *(const float4*)(coords + (size_t)c * D + k8 * 8 + 4);
    short8 hi, lo;
    split8(v, &hi, &lo);
    int ch = c >> 7, nl = c & 127;
    size_t off = (size_t)ch * 16384 + ((size_t)nl * 16 + (k8 ^ (nl & 15))) * 8;
    *(short8*)(Bh + off) = hi;
    *(short8*)(Bl + off) = lo;
    // c2 via 16-lane reduce (lanes [g*16, g*16+15] share c)
    float p = 0.f;
#pragma unroll
    for (int j = 0; j < 8; ++j) p = fmaf(v[j], v[j], p);
#pragma unroll
    for (int m = 1; m <= 8; m <<= 1) p += __shfl_xor(p, m, 64);
    if (k8 == 0) c2[c] = p;
}

// 2M threads: thread t handles row = t>>4, k8 = t&15. Fragment-major layout:
// granule(m_local, k8) = ((m>>4)*4 + (k8>>2))*64 + (k8&3)*16 + (m&15)
__global__ void prep_latent(const float* __restrict__ latent,
                            unsigned short* __restrict__ Ah,
                            unsigned short* __restrict__ Al, int n_rows) {
    int t = blockIdx.x * blockDim.x + threadIdx.x;
    if (t >= n_rows * 16) return;
    int row = t >> 4;
    int k8  = t & 15;
    float v[8];
    *(float4*)(v)     = *(const float4*)(latent + (size_t)row * D + k8 * 8);
    *(float4*)(v + 4) = *(const float4*)(latent + (size_t)row * D + k8 * 8 + 4);
    short8 hi, lo;
    split8(v, &hi, &lo);
    int tile = row >> 7, ml = row & 127;
    size_t g = ((size_t)(ml >> 4) * 4 + (k8 >> 2)) * 64 + (k8 & 3) * 16 + (ml & 15);
    size_t off = (size_t)tile * 16384 + g * 8;
    *(short8*)(Ah + off) = hi;
    *(short8*)(Al + off) = lo;
}

// ---------------- fast-path main kernel ----------------

__global__ __launch_bounds__(256, 1) void centroid_fast(
        const unsigned short* __restrict__ Ah_img,
        const unsigned short* __restrict__ Al_img,
        const unsigned short* __restrict__ Bh_img,
        const unsigned short* __restrict__ Bl_img,
        const float* __restrict__ c2g,
        int* __restrict__ out,
        int* __restrict__ counter,
        int* __restrict__ worklist) {
    __shared__ __align__(16) unsigned short Bh[16384], Bl[16384];  // 64 KB
    __shared__ float sc2[128];
    __shared__ float xb1[128], xb2[128];
    __shared__ int   xix[128];

    const int tid  = threadIdx.x;
    const int wid  = tid >> 6;
    const int lane = tid & 63;
    const int wm   = wid >> 1, wn = wid & 1;
    const int q    = lane >> 4, lr = lane & 15;
    const int tile = blockIdx.x;
    const int row_block = tile * 128;

    // A fragments -> VGPRs, contiguous 1 KB per (mt,ks) per wave.
    short8 Ah[4][4], Al[4][4];
    {
        const size_t tb = (size_t)tile * 16384;
#pragma unroll
        for (int mt = 0; mt < 4; ++mt)
#pragma unroll
            for (int ks = 0; ks < 4; ++ks) {
                size_t off = tb + (size_t)(((wm * 4 + mt) * 4 + ks) * 64 + lane) * 8;
                Ah[mt][ks] = *(const short8*)(Ah_img + off);
                Al[mt][ks] = *(const short8*)(Al_img + off);
            }
    }

    float b1[16], b2[16];
    int   bidx[16];
#pragma unroll
    for (int s = 0; s < 16; ++s) { b1[s] = 3.4e38f; b2[s] = 3.4e38f; bidx[s] = 0; }

    for (int ch = 0; ch < 16; ++ch) {
        __syncthreads();   // prior chunk's ds_reads done
        {   // stage B chunk image: contiguous copy, conflict-free
            const unsigned short* sh = Bh_img + (size_t)ch * 16384;
            const unsigned short* sl = Bl_img + (size_t)ch * 16384;
#pragma unroll
            for (int i = 0; i < 8; ++i) {
                int e = (i * 256 + tid) * 8;
                *(short8*)(Bh + e) = *(const short8*)(sh + e);
                *(short8*)(Bl + e) = *(const short8*)(sl + e);
            }
            if (tid < 128) sc2[tid] = c2g[ch * 128 + tid];
        }
        __syncthreads();

#pragma unroll
        for (int nt = 0; nt < 4; ++nt) {
            const int nl = wn * 64 + nt * 16 + lr;
            f32x4 acc[4];
#pragma unroll
            for (int mt = 0; mt < 4; ++mt) acc[mt] = (f32x4){0.f, 0.f, 0.f, 0.f};
#pragma unroll
            for (int ks = 0; ks < 4; ++ks) {
                const int xv = ((ks * 4) | q) ^ lr;     // swizzle: 8 lanes/bank-quad
                const int e  = nl * 128 + xv * 8;
                short8 bh = *(const short8*)(Bh + e);
                short8 bl = *(const short8*)(Bl + e);
#pragma unroll
                for (int mt = 0; mt < 4; ++mt) {
                    acc[mt] = __builtin_amdgcn_mfma_f32_16x16x32_bf16(Ah[mt][ks], bh, acc[mt], 0, 0, 0);
                    acc[mt] = __builtin_amdgcn_mfma_f32_16x16x32_bf16(Ah[mt][ks], bl, acc[mt], 0, 0, 0);
                    acc[mt] = __builtin_amdgcn_mfma_f32_16x16x32_bf16(Al[mt][ks], bh, acc[mt], 0, 0, 0);
                }
            }
            const float c2v = sc2[nl];
            const int n_global = ch * 128 + nl;
#pragma unroll
            for (int mt = 0; mt < 4; ++mt)
#pragma unroll
                for (int r = 0; r < 4; ++r) {
                    int slot = mt * 4 + r;
                    float s = fmaf(-2.f, acc[mt][r], c2v);
                    bool lt = s < b1[slot];
                    float t = fmaxf(s, b1[slot]);
                    b2[slot]   = fminf(b2[slot], t);
                    b1[slot]   = fminf(s, b1[slot]);
                    bidx[slot] = lt ? n_global : bidx[slot];
                }
        }
    }

    // butterfly over the 16 col-residue lanes
#pragma unroll
    for (int m = 1; m <= 8; m <<= 1) {
#pragma unroll
        for (int s = 0; s < 16; ++s) {
            float ob1 = __shfl_xor(b1[s], m, 64);
            float ob2 = __shfl_xor(b2[s], m, 64);
            int   oix = __shfl_xor(bidx[s], m, 64);
            float mx  = fmaxf(b1[s], ob1);
            b2[s] = fminf(fminf(b2[s], ob2), mx);
            bool take = (ob1 < b1[s]) || (ob1 == b1[s] && oix < bidx[s]);
            b1[s]   = take ? ob1 : b1[s];
            bidx[s] = take ? oix : bidx[s];
        }
    }
    // merge wn halves via LDS exchange; wn=0 writes
    if (wn == 1) {
#pragma unroll
        for (int s = 0; s < 16; ++s)
            if (lr == s) {
                int rw = wm * 64 + (s >> 2) * 16 + q * 4 + (s & 3);
                xb1[rw] = b1[s]; xb2[rw] = b2[s]; xix[rw] = bidx[s];
            }
    }
    __syncthreads();
    if (wn == 0) {
#pragma unroll
        for (int s = 0; s < 16; ++s)
            if (lr == s) {
                int rw = wm * 64 + (s >> 2) * 16 + q * 4 + (s & 3);
                float ob1 = xb1[rw], ob2 = xb2[rw];
                int   oix = xix[rw];
                float mx  = fmaxf(b1[s], ob1);
                float nb2 = fminf(fminf(b2[s], ob2), mx);
                bool take = (ob1 < b1[s]) || (ob1 == b1[s] && oix < bidx[s]);
                float nb1 = take ? ob1 : b1[s];
                int   nix = take ? oix : bidx[s];
                out[row_block + rw] = nix;
                if (nb2 - nb1 < MARGIN) {
                    int w = atomicAdd(counter, 1);
                    if (w < WL_CAP) worklist[w] = row_block + rw;
                }
            }
    }
}

// ---------------- fallback (R3, verified) ----------------

constexpr int LDK = 136;

__global__ void c2_kernel(const float* __restrict__ coords, float* __restrict__ c2,
                          int* __restrict__ counter) {
    int c = blockIdx.x * blockDim.x + threadIdx.x;
    if (c == 0) *counter = 0;
    if (c >= C) return;
    const float* p = coords + (size_t)c * D;
    float s = 0.f;
#pragma unroll
    for (int k = 0; k < D; k += 4) {
        float4 v = *(const float4*)(p + k);
        s = fmaf(v.x, v.x, s); s = fmaf(v.y, v.y, s);
        s = fmaf(v.z, v.z, s); s = fmaf(v.w, v.w, s);
    }
    c2[c] = s;
}

__device__ inline void stage_tile(const float* __restrict__ src,
                                  unsigned short* __restrict__ hi,
                                  unsigned short* __restrict__ lo, int tid) {
#pragma unroll
    for (int i = 0; i < 16; ++i) {
        int f = i * 256 + tid;
        int row = f >> 5, c4 = f & 31;
        float4 v = *(const float4*)(src + (size_t)row * D + c4 * 4);
        unsigned short h0 = bf16_rne(v.x), h1 = bf16_rne(v.y),
                       h2 = bf16_rne(v.z), h3 = bf16_rne(v.w);
        unsigned short l0 = bf16_rne(v.x - bf16_to_f(h0)),
                       l1 = bf16_rne(v.y - bf16_to_f(h1)),
                       l2 = bf16_rne(v.z - bf16_to_f(h2)),
                       l3 = bf16_rne(v.w - bf16_to_f(h3));
        uint2 hp, lp;
        hp.x = (unsigned)h0 | ((unsigned)h1 << 16);
        hp.y = (unsigned)h2 | ((unsigned)h3 << 16);
        lp.x = (unsigned)l0 | ((unsigned)l1 << 16);
        lp.y = (unsigned)l2 | ((unsigned)l3 << 16);
        *(uint2*)(hi + row * LDK + c4 * 4) = hp;
        *(uint2*)(lo + row * LDK + c4 * 4) = lp;
    }
}

__global__ __launch_bounds__(256, 1) void centroid_mfma_v3(
        const float* __restrict__ latent, const float* __restrict__ coords,
        const float* __restrict__ c2g, int* __restrict__ out,
        int* __restrict__ counter, int* __restrict__ worklist, int wl_cap) {
    __shared__ unsigned short A_hi[128 * LDK], A_lo[128 * LDK];
    __shared__ unsigned short B_hi[128 * LDK], B_lo[128 * LDK];
    __shared__ float sc2[128];
    __shared__ float xb1[128], xb2[128];
    __shared__ int   xix[128];

    const int tid = threadIdx.x, wid = tid >> 6, lane = tid & 63;
    const int wm = wid >> 1, wn = wid & 1, q = lane >> 4, lr = lane & 15;
    const int row_block = blockIdx.x * 128;

    stage_tile(latent + (size_t)row_block * D, A_hi, A_lo, tid);

    float b1[16], b2[16];
    int   bidx[16];
#pragma unroll
    for (int s = 0; s < 16; ++s) { b1[s] = 3.4e38f; b2[s] = 3.4e38f; bidx[s] = 0; }

    for (int ch = 0; ch < 16; ++ch) {
        __syncthreads();
        stage_tile(coords + (size_t)ch * 128 * D, B_hi, B_lo, tid);
        if (tid < 128) sc2[tid] = c2g[ch * 128 + tid];
        __syncthreads();

        f32x4 acc[4][4];
#pragma unroll
        for (int mt = 0; mt < 4; ++mt)
#pragma unroll
            for (int nt = 0; nt < 4; ++nt) acc[mt][nt] = (f32x4){0.f, 0.f, 0.f, 0.f};

#pragma unroll
        for (int ks = 0; ks < 4; ++ks) {
            short8 ah[4], al[4], bh[4], bl[4];
#pragma unroll
            for (int mt = 0; mt < 4; ++mt) {
                int off = (wm * 64 + mt * 16 + lr) * LDK + ks * 32 + q * 8;
                ah[mt] = *(const short8*)(A_hi + off);
                al[mt] = *(const short8*)(A_lo + off);
            }
#pragma unroll
            for (int nt = 0; nt < 4; ++nt) {
                int off = (wn * 64 + nt * 16 + lr) * LDK + ks * 32 + q * 8;
                bh[nt] = *(const short8*)(B_hi + off);
                bl[nt] = *(const short8*)(B_lo + off);
            }
#pragma unroll
            for (int mt = 0; mt < 4; ++mt)
#pragma unroll
                for (int nt = 0; nt < 4; ++nt) {
                    acc[mt][nt] = __builtin_amdgcn_mfma_f32_16x16x32_bf16(ah[mt], bh[nt], acc[mt][nt], 0, 0, 0);
                    acc[mt][nt] = __builtin_amdgcn_mfma_f32_16x16x32_bf16(ah[mt], bl[nt], acc[mt][nt], 0, 0, 0);
                    acc[mt][nt] = __builtin_amdgcn_mfma_f32_16x16x32_bf16(al[mt], bh[nt], acc[mt][nt], 0, 0, 0);
                }
        }
#pragma unroll
        for (int nt = 0; nt < 4; ++nt) {
            int cix = wn * 64 + nt * 16 + lr;
            float c2v = sc2[cix];
            int n_global = ch * 128 + cix;
#pragma unroll
            for (int mt = 0; mt < 4; ++mt)
#pragma unroll
                for (int r = 0; r < 4; ++r) {
                    int slot = mt * 4 + r;
                    float s = fmaf(-2.f, acc[mt][nt][r], c2v);
                    bool lt = s < b1[slot];
                    float t = fmaxf(s, b1[slot]);
                    b2[slot]   = fminf(b2[slot], t);
                    b1[slot]   = fminf(s, b1[slot]);
                    bidx[slot] = lt ? n_global : bidx[slot];
                }
        }
    }
#pragma unroll
    for (int m = 1; m <= 8; m <<= 1) {
#pragma unroll
        for (int s = 0; s < 16; ++s) {
            float ob1 = __shfl_xor(b1[s], m, 64);
            float ob2 = __shfl_xor(b2[s], m, 64);
            int   oix = __shfl_xor(bidx[s], m, 64);
            float mx  = fmaxf(b1[s], ob1);
            b2[s] = fminf(fminf(b2[s], ob2), mx);
            bool take = (ob1 < b1[s]) || (ob1 == b1[s] && oix < bidx[s]);
            b1[s]   = take ? ob1 : b1[s];
            bidx[s] = take ? oix : bidx[s];
        }
    }
    if (wn == 1) {
#pragma unroll
        for (int s = 0; s < 16; ++s)
            if (lr == s) {
                int rw = wm * 64 + (s >> 2) * 16 + q * 4 + (s & 3);
                xb1[rw] = b1[s]; xb2[rw] = b2[s]; xix[rw] = bidx[s];
            }
    }
    __syncthreads();
    if (wn == 0) {
#pragma unroll
        for (int s = 0; s < 16; ++s)
            if (lr == s) {
                int rw = wm * 64 + (s >> 2) * 16 + q * 4 + (s & 3);
                float ob1 = xb1[rw], ob2 = xb2[rw];
                int   oix = xix[rw];
                float mx  = fmaxf(b1[s], ob1);
                float nb2 = fminf(fminf(b2[s], ob2), mx);
                bool take = (ob1 < b1[s]) || (ob1 == b1[s] && oix < bidx[s]);
                float nb1 = take ? ob1 : b1[s];
                int   nix = take ? oix : bidx[s];
                out[row_block + rw] = nix;
                if (nb2 - nb1 < MARGIN) {
                    int w = atomicAdd(counter, 1);
                    if (w < wl_cap) worklist[w] = row_block + rw;
                }
            }
    }
}

// ---------------- fp64 refine ----------------

__global__ __launch_bounds__(256) void refine_fp64(
        const float* __restrict__ latent, const float* __restrict__ coords,
        const int* __restrict__ worklist, const int* __restrict__ counter,
        int wl_cap, int* __restrict__ out) {
    __shared__ float  xs[D];
    __shared__ double rv[256];
    __shared__ int    ri[256];

    int n = *counter;
    if (n > wl_cap) n = wl_cap;

    for (int wi = blockIdx.x; wi < n; wi += gridDim.x) {
        int row = worklist[wi];
        if (threadIdx.x < D)
            xs[threadIdx.x] = latent[(size_t)row * D + threadIdx.x];
        __syncthreads();

        double best = 1.0e300;
        int    bix  = 0;
        for (int c = threadIdx.x; c < C; c += 256) {
            const float4* cp = (const float4*)(coords + (size_t)c * D);
            double s = 0.0;
#pragma unroll 8
            for (int k4 = 0; k4 < 32; ++k4) {
                float4 v = cp[k4];
                double d0 = (double)xs[k4 * 4 + 0] - (double)v.x;
                double d1 = (double)xs[k4 * 4 + 1] - (double)v.y;
                double d2 = (double)xs[k4 * 4 + 2] - (double)v.z;
                double d3 = (double)xs[k4 * 4 + 3] - (double)v.w;
                s = fma(d0, d0, s); s = fma(d1, d1, s);
                s = fma(d2, d2, s); s = fma(d3, d3, s);
            }
            if (s < best) { best = s; bix = c; }
        }
        rv[threadIdx.x] = best;
        ri[threadIdx.x] = bix;
        __syncthreads();
        for (int off = 128; off > 0; off >>= 1) {
            if (threadIdx.x < off) {
                double ov = rv[threadIdx.x + off];
                int    oi = ri[threadIdx.x + off];
                if (ov < rv[threadIdx.x] ||
                    (ov == rv[threadIdx.x] && oi < ri[threadIdx.x])) {
                    rv[threadIdx.x] = ov;
                    ri[threadIdx.x] = oi;
                }
            }
            __syncthreads();
        }
        if (threadIdx.x == 0) out[row] = ri[0];
        __syncthreads();
    }
}

extern "C" void kernel_launch(void* const* d_in, const int* in_sizes, int n_in,
                              void* d_out, int out_size, void* d_ws, size_t ws_size,
                              hipStream_t stream) {
    const float* latent = (const float*)d_in[0];
    const float* coords = (const float*)d_in[1];
    int*         out    = (int*)d_out;

    char* ws = (char*)d_ws;
    float* c2      = (float*)ws;
    int*   counter = (int*)(ws + WS_CNT);
    int*   wl      = (int*)(ws + WS_WL);
    const int n_rows = in_sizes[0] / D;   // 131072

    if (ws_size >= WS_END) {
        unsigned short* Bh = (unsigned short*)(ws + WS_BH);
        unsigned short* Bl = (unsigned short*)(ws + WS_BL);
        unsigned short* Ah = (unsigned short*)(ws + WS_AH);
        unsigned short* Al = (unsigned short*)(ws + WS_AL);
        prep_coords<<<(C * 16) / 256, 256, 0, stream>>>(coords, Bh, Bl, c2, counter);
        prep_latent<<<(n_rows * 16) / 256, 256, 0, stream>>>(latent, Ah, Al, n_rows);
        centroid_fast<<<n_rows / 128, 256, 0, stream>>>(Ah, Al, Bh, Bl, c2, out,
                                                        counter, wl);
        refine_fp64<<<608, 256, 0, stream>>>(latent, coords, wl, counter, WL_CAP, out);
    } else {
        long long cap_ll = (long long)(ws_size / 4) - 4096 - 2048;
        int wl_cap = cap_ll < 0 ? 0 : (cap_ll > WL_CAP ? WL_CAP : (int)cap_ll);
        c2_kernel<<<(C + 255) / 256, 256, 0, stream>>>(coords, c2, counter);
        centroid_mfma_v3<<<n_rows / 128, 256, 0, stream>>>(latent, coords, c2, out,
                                                           counter, wl, wl_cap);
        refine_fp64<<<608, 256, 0, stream>>>(latent, coords, wl, counter, wl_cap, out);
    }
}